// Round 3
// baseline (923.538 us; speedup 1.0000x reference)
//
#include <hip/hip_runtime.h>

#define T_TOK 4096
#define DDIM  2048
#define NEXP  8
#define HDIM  1024
#define HSDIM 2048
#define NASSIGN 8192    // T_TOK * TOP_K
#define MAXTILES 40     // sum ceil(n_e/256) <= 8192/256 + 8

typedef __attribute__((ext_vector_type(8))) short bf16x8;
typedef __attribute__((ext_vector_type(4))) float f32x4;

__device__ __forceinline__ ushort f2bf(float f) {
  union { float f; unsigned u; } v; v.f = f;
  unsigned r = v.u + 0x7FFFu + ((v.u >> 16) & 1u);
  return (ushort)(r >> 16);
}
__device__ __forceinline__ float bf2f(ushort s) {
  union { float f; unsigned u; } v; v.u = ((unsigned)s) << 16;
  return v.f;
}
__device__ __forceinline__ void gload16(const void* g, void* s) {
  __builtin_amdgcn_global_load_lds((const __attribute__((address_space(1))) void*)g,
                                   (__attribute__((address_space(3))) void*)s, 16, 0, 0);
}
// bijective XCD swizzle (m204): nwg need not be %8
__device__ __forceinline__ int xcd_swz(int orig, int nwg) {
  int q = nwg >> 3, r = nwg & 7;
  int xcd = orig & 7, pos = orig >> 3;
  return (xcd < r ? xcd * (q + 1) : r * (q + 1) + (xcd - r) * q) + pos;
}

// ---------------- control block (ints) ----------------
// [0] ntiles | [8..15] cnt | [16..23] cursor | [24..32] off
// [64..103] tile_expert | [160..199] tile_row0 | [256..295] tile_end

__global__ void zero_k(int* ctl) {
  int i = threadIdx.x;
#pragma unroll
  for (int j = 0; j < 4; ++j) ctl[i + j * 256] = 0;
}

__global__ void router_k(const float* __restrict__ x, const float* __restrict__ rw,
                         int* __restrict__ ctl, int* __restrict__ tidx,
                         float* __restrict__ twt) {
  int t = blockIdx.x;
  int lane = threadIdx.x;
  const float* xr = x + (size_t)t * DDIM;
  float acc[NEXP];
#pragma unroll
  for (int e = 0; e < NEXP; ++e) acc[e] = 0.f;
  for (int d0 = lane * 4; d0 < DDIM; d0 += 256) {
    float4 xv = *(const float4*)(xr + d0);
    const float* rwp = rw + (size_t)d0 * NEXP;
#pragma unroll
    for (int e = 0; e < NEXP; ++e)
      acc[e] += xv.x * rwp[e] + xv.y * rwp[NEXP + e] +
                xv.z * rwp[2 * NEXP + e] + xv.w * rwp[3 * NEXP + e];
  }
#pragma unroll
  for (int e = 0; e < NEXP; ++e) {
#pragma unroll
    for (int off = 32; off >= 1; off >>= 1) acc[e] += __shfl_xor(acc[e], off, 64);
  }
  if (lane == 0) {
    int i0 = 0; float m0 = acc[0];
#pragma unroll
    for (int e = 1; e < NEXP; ++e) if (acc[e] > m0) { m0 = acc[e]; i0 = e; }
    int i1 = -1; float m1 = -3.4e38f;
#pragma unroll
    for (int e = 0; e < NEXP; ++e) if (e != i0 && acc[e] > m1) { m1 = acc[e]; i1 = e; }
    float w0 = 1.f / (1.f + __expf(m1 - m0));
    float w1 = 1.f - w0;
    tidx[2 * t] = i0;     twt[2 * t] = w0;
    tidx[2 * t + 1] = i1; twt[2 * t + 1] = w1;
    atomicAdd(&ctl[8 + i0], 1);
    atomicAdd(&ctl[8 + i1], 1);
  }
}

__global__ void plan_k(int* ctl) {
  if (threadIdx.x != 0 || blockIdx.x != 0) return;
  int off = 0, nt = 0;
  for (int e = 0; e < NEXP; ++e) {
    int c = ctl[8 + e];
    ctl[24 + e] = off;
    ctl[16 + e] = off;
    int ntile = (c + 255) >> 8;
    for (int j = 0; j < ntile; ++j) {
      ctl[64 + nt] = e;
      ctl[160 + nt] = off + j * 256;
      ctl[256 + nt] = off + c;
      ++nt;
    }
    off += c;
  }
  ctl[24 + NEXP] = off;
  ctl[0] = nt;
}

__global__ void scatter_k(const int* __restrict__ tidx, const float* __restrict__ twt,
                          int* __restrict__ ctl, int* __restrict__ stok,
                          float* __restrict__ swt) {
  int t = blockIdx.x * blockDim.x + threadIdx.x;
  if (t >= T_TOK) return;
#pragma unroll
  for (int k = 0; k < 2; ++k) {
    int e = tidx[2 * t + k];
    int p = atomicAdd(&ctl[16 + e], 1);
    stok[p] = t;
    swt[p] = twt[2 * t + k];
  }
}

__global__ void cvt_k(const float* __restrict__ in, ushort* __restrict__ out) {
  long long i = ((long long)blockIdx.x * blockDim.x + threadIdx.x) * 8;
  float4 a = *(const float4*)(in + i);
  float4 b = *(const float4*)(in + i + 4);
  ushort4 o0 = { f2bf(a.x), f2bf(a.y), f2bf(a.z), f2bf(a.w) };
  ushort4 o1 = { f2bf(b.x), f2bf(b.y), f2bf(b.z), f2bf(b.w) };
  *(ushort4*)(out + i) = o0;
  *(ushort4*)(out + i + 4) = o1;
}

// [R][C] f32 -> [C][R] bf16 transpose+convert; z slice strides passed separately
__global__ void tcvt_k(const float* __restrict__ in, ushort* __restrict__ out,
                       int R, int C, long long inZ, long long outZ) {
  __shared__ float tile[64][65];
  in  += (size_t)blockIdx.z * inZ;
  out += (size_t)blockIdx.z * outZ;
  int c0 = blockIdx.x * 64, r0 = blockIdx.y * 64;
  int tx = threadIdx.x & 15, ty = threadIdx.x >> 4;
#pragma unroll
  for (int i = 0; i < 4; ++i) {
    float4 v = *(const float4*)(in + (size_t)(r0 + ty + 16 * i) * C + c0 + tx * 4);
    tile[ty + 16 * i][tx * 4 + 0] = v.x;
    tile[ty + 16 * i][tx * 4 + 1] = v.y;
    tile[ty + 16 * i][tx * 4 + 2] = v.z;
    tile[ty + 16 * i][tx * 4 + 3] = v.w;
  }
  __syncthreads();
#pragma unroll
  for (int i = 0; i < 4; ++i) {
    ushort4 o = { f2bf(tile[tx * 4 + 0][ty + 16 * i]),
                  f2bf(tile[tx * 4 + 1][ty + 16 * i]),
                  f2bf(tile[tx * 4 + 2][ty + 16 * i]),
                  f2bf(tile[tx * 4 + 3][ty + 16 * i]) };
    *(ushort4*)(out + (size_t)(c0 + ty + 16 * i) * R + r0 + tx * 4) = o;
  }
}

// h = silu(g) * u, with g,u column-halves of GU [M][2N]; h [M][N]
__global__ void silu_k(const ushort* __restrict__ gu, ushort* __restrict__ h, int N) {
  int row = blockIdx.x, c = threadIdx.x * 8;
  const ushort* gp = gu + (size_t)row * 2 * N;
  bf16x8 gv = *(const bf16x8*)(gp + c);
  bf16x8 uv = *(const bf16x8*)(gp + N + c);
  ushort o[8];
#pragma unroll
  for (int k = 0; k < 8; ++k) {
    float gf = bf2f((ushort)gv[k]);
    float uf = bf2f((ushort)uv[k]);
    float hv = gf / (1.f + __expf(-gf)) * uf;
    o[k] = f2bf(hv);
  }
  ushort4 o0 = { o[0], o[1], o[2], o[3] };
  ushort4 o1 = { o[4], o[5], o[6], o[7] };
  *(ushort4*)(h + (size_t)row * N + c) = o0;
  *(ushort4*)(h + (size_t)row * N + c + 4) = o1;
}

// ======== 256x256 2-phase double-buffered GEMM: GU_cat = A @ Bcat^T ========
// A [*, 2048] bf16 (rows gathered via toks); Bcat [Ncat][2048] bf16 (per-expert for ROUTED)
// out GU bf16 [rows][Ncat]. 512 thr = 8 waves (2M x 4N), per-wave 128x64. LDS 128 KiB.
template <bool ROUTED>
__global__ __launch_bounds__(512, 2) void gucat_k(
    const ushort* __restrict__ Ax, const ushort* __restrict__ Bcat,
    ushort* __restrict__ GU, const int* __restrict__ ctl,
    const int* __restrict__ stok, int Ncat) {
  __shared__ ushort As[2][256 * 64];
  __shared__ ushort Bs[2][256 * 64];
  __shared__ int toks[256];

  int nwg = gridDim.x * gridDim.y;
  int wg = xcd_swz(blockIdx.y * gridDim.x + blockIdx.x, nwg);
  int mt = wg % gridDim.x, ntt = wg / gridDim.x;

  int tid = threadIdx.x;
  int row0, nrows;
  const ushort* Bp;
  if (ROUTED) {
    if (mt >= ctl[0]) return;
    row0 = ctl[160 + mt];
    int end = ctl[256 + mt];
    nrows = end - row0; if (nrows > 256) nrows = 256;
    Bp = Bcat + (size_t)ctl[64 + mt] * (2048 * 2048);
    if (tid < 256) toks[tid] = (tid < nrows) ? stok[row0 + tid] : 0;
  } else {
    row0 = mt * 256; nrows = 256;
    Bp = Bcat;
    if (tid < 256) toks[tid] = row0 + tid;
  }
  int col0 = ntt * 256;
  __syncthreads();

  int srow = tid >> 3, skc = (tid & 7) * 8;
  const ushort* aSrc[4];
  const ushort* bSrc[4];
#pragma unroll
  for (int rr = 0; rr < 4; ++rr) {
    aSrc[rr] = Ax + (size_t)toks[rr * 64 + srow] * DDIM + skc;
    bSrc[rr] = Bp + (size_t)(col0 + rr * 64 + srow) * DDIM + skc;
  }

  int lane = tid & 63, w = tid >> 6;
  int g = lane >> 4, r16 = lane & 15;
  int wrow = (w >> 2) * 128, wcol = (w & 3) * 64;

  f32x4 acc[8][4];
  f32x4 z = {0.f, 0.f, 0.f, 0.f};
#pragma unroll
  for (int i = 0; i < 8; ++i)
#pragma unroll
    for (int j = 0; j < 4; ++j) acc[i][j] = z;

#define STAGE_GU(buf, k0)                                          \
  {                                                                 \
    _Pragma("unroll")                                               \
    for (int rr = 0; rr < 4; ++rr) {                                \
      gload16(aSrc[rr] + (k0), &As[buf][(rr * 512 + tid) * 8]);     \
      gload16(bSrc[rr] + (k0), &Bs[buf][(rr * 512 + tid) * 8]);     \
    }                                                               \
  }
#define COMPUTE_GU(buf)                                                              \
  {                                                                                   \
    _Pragma("unroll")                                                                 \
    for (int kk = 0; kk < 2; ++kk) {                                                  \
      bf16x8 af[8], bf_[4];                                                           \
      _Pragma("unroll")                                                               \
      for (int mf = 0; mf < 8; ++mf)                                                  \
        af[mf] = *(const bf16x8*)(&As[buf][(wrow + mf * 16 + r16) * 64 + kk * 32 + g * 8]); \
      _Pragma("unroll")                                                               \
      for (int nf = 0; nf < 4; ++nf)                                                  \
        bf_[nf] = *(const bf16x8*)(&Bs[buf][(wcol + nf * 16 + r16) * 64 + kk * 32 + g * 8]); \
      _Pragma("unroll")                                                               \
      for (int mf = 0; mf < 8; ++mf)                                                  \
        _Pragma("unroll")                                                             \
        for (int nf = 0; nf < 4; ++nf)                                                \
          acc[mf][nf] = __builtin_amdgcn_mfma_f32_16x16x32_bf16(af[mf], bf_[nf], acc[mf][nf], 0, 0, 0); \
    }                                                                                 \
  }

  STAGE_GU(0, 0);
  __syncthreads();
  int cur = 0;
  for (int k0 = 64; k0 < DDIM; k0 += 64) {
    STAGE_GU(cur ^ 1, k0);   // prefetch next tile while computing current
    COMPUTE_GU(cur);
    __syncthreads();         // drains vmcnt(0): prefetch landed; buffer reuse safe
    cur ^= 1;
  }
  COMPUTE_GU(cur);

#pragma unroll
  for (int mf = 0; mf < 8; ++mf) {
#pragma unroll
    for (int j = 0; j < 4; ++j) {
      int rloc = wrow + mf * 16 + g * 4 + j;
      if (rloc < nrows) {
        size_t ob = (size_t)(row0 + rloc) * Ncat + col0 + wcol;
#pragma unroll
        for (int nf = 0; nf < 4; ++nf)
          GU[ob + nf * 16 + r16] = f2bf(acc[mf][nf][j]);
      }
    }
  }
#undef STAGE_GU
#undef COMPUTE_GU
}

// ======== routed down: 256x256, K=1024, weighted atomic epilogue ========
__global__ __launch_bounds__(512, 2) void downR_k(
    const ushort* __restrict__ Ah, const ushort* __restrict__ BdT,
    float* __restrict__ Out, const int* __restrict__ ctl,
    const int* __restrict__ stok, const float* __restrict__ swt) {
  __shared__ ushort As[2][256 * 64];
  __shared__ ushort Bs[2][256 * 64];
  __shared__ int tokl[256];
  __shared__ float wtl[256];

  int nwg = gridDim.x * gridDim.y;
  int wg = xcd_swz(blockIdx.y * gridDim.x + blockIdx.x, nwg);
  int mt = wg % gridDim.x, ntt = wg / gridDim.x;

  int tid = threadIdx.x;
  if (mt >= ctl[0]) return;
  int row0 = ctl[160 + mt];
  int end = ctl[256 + mt];
  int nrows = end - row0; if (nrows > 256) nrows = 256;
  const ushort* Bp = BdT + (size_t)ctl[64 + mt] * (2048 * 1024);
  if (tid < 256) {
    bool v = tid < nrows;
    tokl[tid] = v ? stok[row0 + tid] : 0;
    wtl[tid] = v ? swt[row0 + tid] : 0.f;
  }
  int col0 = ntt * 256;
  __syncthreads();

  int srow = tid >> 3, skc = (tid & 7) * 8;
  const ushort* aSrc[4];
  const ushort* bSrc[4];
#pragma unroll
  for (int rr = 0; rr < 4; ++rr) {
    aSrc[rr] = Ah + (size_t)(row0 + rr * 64 + srow) * HDIM + skc;  // Ah padded +256 rows
    bSrc[rr] = Bp + (size_t)(col0 + rr * 64 + srow) * HDIM + skc;
  }

  int lane = tid & 63, w = tid >> 6;
  int g = lane >> 4, r16 = lane & 15;
  int wrow = (w >> 2) * 128, wcol = (w & 3) * 64;

  f32x4 acc[8][4];
  f32x4 z = {0.f, 0.f, 0.f, 0.f};
#pragma unroll
  for (int i = 0; i < 8; ++i)
#pragma unroll
    for (int j = 0; j < 4; ++j) acc[i][j] = z;

#define STAGE_DR(buf, k0)                                          \
  {                                                                 \
    _Pragma("unroll")                                               \
    for (int rr = 0; rr < 4; ++rr) {                                \
      gload16(aSrc[rr] + (k0), &As[buf][(rr * 512 + tid) * 8]);     \
      gload16(bSrc[rr] + (k0), &Bs[buf][(rr * 512 + tid) * 8]);     \
    }                                                               \
  }
#define COMPUTE_DR(buf)                                                              \
  {                                                                                   \
    _Pragma("unroll")                                                                 \
    for (int kk = 0; kk < 2; ++kk) {                                                  \
      bf16x8 af[8], bf_[4];                                                           \
      _Pragma("unroll")                                                               \
      for (int mf = 0; mf < 8; ++mf)                                                  \
        af[mf] = *(const bf16x8*)(&As[buf][(wrow + mf * 16 + r16) * 64 + kk * 32 + g * 8]); \
      _Pragma("unroll")                                                               \
      for (int nf = 0; nf < 4; ++nf)                                                  \
        bf_[nf] = *(const bf16x8*)(&Bs[buf][(wcol + nf * 16 + r16) * 64 + kk * 32 + g * 8]); \
      _Pragma("unroll")                                                               \
      for (int mf = 0; mf < 8; ++mf)                                                  \
        _Pragma("unroll")                                                             \
        for (int nf = 0; nf < 4; ++nf)                                                \
          acc[mf][nf] = __builtin_amdgcn_mfma_f32_16x16x32_bf16(af[mf], bf_[nf], acc[mf][nf], 0, 0, 0); \
    }                                                                                 \
  }

  STAGE_DR(0, 0);
  __syncthreads();
  int cur = 0;
  for (int k0 = 64; k0 < HDIM; k0 += 64) {
    STAGE_DR(cur ^ 1, k0);
    COMPUTE_DR(cur);
    __syncthreads();
    cur ^= 1;
  }
  COMPUTE_DR(cur);

#pragma unroll
  for (int mf = 0; mf < 8; ++mf) {
#pragma unroll
    for (int j = 0; j < 4; ++j) {
      int rloc = wrow + mf * 16 + g * 4 + j;
      if (rloc < nrows) {
        int t = tokl[rloc];
        float wt = wtl[rloc];
        size_t ob = (size_t)t * DDIM + col0 + wcol;
#pragma unroll
        for (int nf = 0; nf < 4; ++nf)
          atomicAdd(&Out[ob + nf * 16 + r16], wt * acc[mf][nf][j]);
      }
    }
  }
#undef STAGE_DR
#undef COMPUTE_DR
}

// ======== shared down: 128x256 tile, K=2048, plain f32 store ========
__global__ __launch_bounds__(512, 2) void downS_k(
    const ushort* __restrict__ Ah, const ushort* __restrict__ BdT,
    float* __restrict__ Out) {
  __shared__ ushort As[2][128 * 64];
  __shared__ ushort Bs[2][256 * 64];

  int nwg = gridDim.x * gridDim.y;
  int wg = xcd_swz(blockIdx.y * gridDim.x + blockIdx.x, nwg);
  int mt = wg % gridDim.x, ntt = wg / gridDim.x;
  int row0 = mt * 128, col0 = ntt * 256;

  int tid = threadIdx.x;
  int srow = tid >> 3, skc = (tid & 7) * 8;
  const ushort* aSrc[2];
  const ushort* bSrc[4];
#pragma unroll
  for (int rr = 0; rr < 2; ++rr)
    aSrc[rr] = Ah + (size_t)(row0 + rr * 64 + srow) * HSDIM + skc;
#pragma unroll
  for (int rr = 0; rr < 4; ++rr)
    bSrc[rr] = BdT + (size_t)(col0 + rr * 64 + srow) * HSDIM + skc;

  int lane = tid & 63, w = tid >> 6;
  int g = lane >> 4, r16 = lane & 15;
  int wrow = (w >> 2) * 64, wcol = (w & 3) * 64;

  f32x4 acc[4][4];
  f32x4 z = {0.f, 0.f, 0.f, 0.f};
#pragma unroll
  for (int i = 0; i < 4; ++i)
#pragma unroll
    for (int j = 0; j < 4; ++j) acc[i][j] = z;

#define STAGE_DS(buf, k0)                                          \
  {                                                                 \
    _Pragma("unroll")                                               \
    for (int rr = 0; rr < 2; ++rr)                                  \
      gload16(aSrc[rr] + (k0), &As[buf][(rr * 512 + tid) * 8]);     \
    _Pragma("unroll")                                               \
    for (int rr = 0; rr < 4; ++rr)                                  \
      gload16(bSrc[rr] + (k0), &Bs[buf][(rr * 512 + tid) * 8]);     \
  }
#define COMPUTE_DS(buf)                                                              \
  {                                                                                   \
    _Pragma("unroll")                                                                 \
    for (int kk = 0; kk < 2; ++kk) {                                                  \
      bf16x8 af[4], bf_[4];                                                           \
      _Pragma("unroll")                                                               \
      for (int mf = 0; mf < 4; ++mf)                                                  \
        af[mf] = *(const bf16x8*)(&As[buf][(wrow + mf * 16 + r16) * 64 + kk * 32 + g * 8]); \
      _Pragma("unroll")                                                               \
      for (int nf = 0; nf < 4; ++nf)                                                  \
        bf_[nf] = *(const bf16x8*)(&Bs[buf][(wcol + nf * 16 + r16) * 64 + kk * 32 + g * 8]); \
      _Pragma("unroll")                                                               \
      for (int mf = 0; mf < 4; ++mf)                                                  \
        _Pragma("unroll")                                                             \
        for (int nf = 0; nf < 4; ++nf)                                                \
          acc[mf][nf] = __builtin_amdgcn_mfma_f32_16x16x32_bf16(af[mf], bf_[nf], acc[mf][nf], 0, 0, 0); \
    }                                                                                 \
  }

  STAGE_DS(0, 0);
  __syncthreads();
  int cur = 0;
  for (int k0 = 64; k0 < HSDIM; k0 += 64) {
    STAGE_DS(cur ^ 1, k0);
    COMPUTE_DS(cur);
    __syncthreads();
    cur ^= 1;
  }
  COMPUTE_DS(cur);

#pragma unroll
  for (int mf = 0; mf < 4; ++mf) {
#pragma unroll
    for (int j = 0; j < 4; ++j) {
      int rloc = wrow + mf * 16 + g * 4 + j;
      size_t ob = (size_t)(row0 + rloc) * DDIM + col0 + wcol;
#pragma unroll
      for (int nf = 0; nf < 4; ++nf)
        Out[ob + nf * 16 + r16] = acc[mf][nf][j];
    }
  }
#undef STAGE_DS
#undef COMPUTE_DS
}

extern "C" void kernel_launch(void* const* d_in, const int* in_sizes, int n_in,
                              void* d_out, int out_size, void* d_ws, size_t ws_size,
                              hipStream_t stream) {
  const float* x   = (const float*)d_in[0];
  const float* rw  = (const float*)d_in[1];
  const float* wg  = (const float*)d_in[2];
  const float* wu  = (const float*)d_in[3];
  const float* wd  = (const float*)d_in[4];
  const float* swg = (const float*)d_in[5];
  const float* swu = (const float*)d_in[6];
  const float* swd = (const float*)d_in[7];
  float* out = (float*)d_out;

  char* ws = (char*)d_ws;
  size_t off = 0;
  auto alloc = [&](size_t bytes) {
    char* p = ws + off;
    off += (bytes + 4095) & ~(size_t)4095;
    return p;
  };
  int*    ctl   = (int*)alloc(4096);
  int*    tidx  = (int*)alloc(NASSIGN * 4);
  float*  twt   = (float*)alloc(NASSIGN * 4);
  int*    stok  = (int*)alloc(NASSIGN * 4);
  float*  swt_  = (float*)alloc(NASSIGN * 4);
  ushort* xbf   = (ushort*)alloc((size_t)T_TOK * DDIM * 2);
  // routed gate|up concat: per expert [2048 n][2048 k]; gate rows 0..1023, up rows 1024..2047
  ushort* catR  = (ushort*)alloc((size_t)NEXP * 2048 * 2048 * 2);
  ushort* wdT   = (ushort*)alloc((size_t)NEXP * DDIM * HDIM * 2);
  // shared gate|up concat: [4096 n][2048 k]
  ushort* catS  = (ushort*)alloc((size_t)2 * HSDIM * DDIM * 2);
  ushort* swdT  = (ushort*)alloc((size_t)DDIM * HSDIM * 2);
  // GU shared between routed [8192][2048] and shared [4096][4096] (same 32 MB; sequenced)
  ushort* GU    = (ushort*)alloc((size_t)NASSIGN * 2048 * 2);
  ushort* hr    = (ushort*)alloc((size_t)(NASSIGN + 256) * HDIM * 2);  // +256 row pad for tail staging
  ushort* hs    = (ushort*)alloc((size_t)T_TOK * HSDIM * 2);
  (void)alloc(1 << 20);  // guard pad
  if (off > ws_size) return;

  // routing chain
  zero_k<<<1, 256, 0, stream>>>(ctl);
  router_k<<<T_TOK, 64, 0, stream>>>(x, rw, ctl, tidx, twt);
  plan_k<<<1, 64, 0, stream>>>(ctl);
  scatter_k<<<16, 256, 0, stream>>>(tidx, twt, ctl, stok, swt_);

  // precision/layout prepasses
  cvt_k<<<(T_TOK * DDIM / 8) / 256, 256, 0, stream>>>(x, xbf);
  tcvt_k<<<dim3(HDIM / 64, DDIM / 64, NEXP), 256, 0, stream>>>(
      wg, catR, DDIM, HDIM, (long long)DDIM * HDIM, 2048LL * 2048);
  tcvt_k<<<dim3(HDIM / 64, DDIM / 64, NEXP), 256, 0, stream>>>(
      wu, catR + 1024 * 2048, DDIM, HDIM, (long long)DDIM * HDIM, 2048LL * 2048);
  tcvt_k<<<dim3(DDIM / 64, HDIM / 64, NEXP), 256, 0, stream>>>(
      wd, wdT, HDIM, DDIM, (long long)HDIM * DDIM, 2048LL * 1024);
  tcvt_k<<<dim3(HSDIM / 64, DDIM / 64, 1), 256, 0, stream>>>(
      swg, catS, DDIM, HSDIM, 0, 0);
  tcvt_k<<<dim3(HSDIM / 64, DDIM / 64, 1), 256, 0, stream>>>(
      swu, catS + 2048 * 2048, DDIM, HSDIM, 0, 0);
  tcvt_k<<<dim3(DDIM / 64, HSDIM / 64, 1), 256, 0, stream>>>(
      swd, swdT, HSDIM, DDIM, 0, 0);

  // routed gate+up -> silu -> (GU freed)
  gucat_k<true><<<dim3(MAXTILES, 2048 / 256), 512, 0, stream>>>(xbf, catR, GU, ctl, stok, 2048);
  silu_k<<<NASSIGN, HDIM / 8, 0, stream>>>(GU, hr, HDIM);
  // shared gate+up -> silu
  gucat_k<false><<<dim3(T_TOK / 256, 4096 / 256), 512, 0, stream>>>(xbf, catS, GU, ctl, stok, 4096);
  silu_k<<<T_TOK, HSDIM / 8, 0, stream>>>(GU, hs, HSDIM);

  // down: shared stores all of out, then routed atomically adds
  downS_k<<<dim3(T_TOK / 128, DDIM / 256), 512, 0, stream>>>(hs, swdT, out);
  downR_k<<<dim3(MAXTILES, DDIM / 256), 512, 0, stream>>>(hr, wdT, out, ctl, stok, swt_);
}

// Round 4
// 841.152 us; speedup vs baseline: 1.0979x; 1.0979x over previous
//
#include <hip/hip_runtime.h>

#define T_TOK 4096
#define DDIM  2048
#define NEXP  8
#define HDIM  1024
#define HSDIM 2048
#define NASSIGN 8192   // T_TOK * TOP_K
#define MAXTILES 72    // sum ceil(n_e/128) <= 8192/128 + 8

typedef __attribute__((ext_vector_type(8))) short bf16x8;
typedef __attribute__((ext_vector_type(4))) float f32x4;

__device__ __forceinline__ ushort f2bf(float f) {
  union { float f; unsigned u; } v; v.f = f;
  unsigned r = v.u + 0x7FFFu + ((v.u >> 16) & 1u);
  return (ushort)(r >> 16);
}
__device__ __forceinline__ void gload16(const void* g, void* s) {
  __builtin_amdgcn_global_load_lds((const __attribute__((address_space(1))) void*)g,
                                   (__attribute__((address_space(3))) void*)s, 16, 0, 0);
}
// bijective XCD swizzle (m204)
__device__ __forceinline__ int xcd_swz(int orig, int nwg) {
  int q = nwg >> 3, r = nwg & 7;
  int xcd = orig & 7, pos = orig >> 3;
  return (xcd < r ? xcd * (q + 1) : r * (q + 1) + (xcd - r) * q) + pos;
}

// ---------------- control block (ints) ----------------
// [0] ntiles | [8..15] cnt | [16..23] cursor | [24..32] off
// [64..143] tile_expert | [160..239] tile_row0 | [256..335] tile_end

__global__ void zero_k(int* ctl) {
  int i = threadIdx.x;
#pragma unroll
  for (int j = 0; j < 4; ++j) ctl[i + j * 256] = 0;
}

__global__ void router_k(const float* __restrict__ x, const float* __restrict__ rw,
                         int* __restrict__ ctl, int* __restrict__ tidx,
                         float* __restrict__ twt) {
  int t = blockIdx.x;
  int lane = threadIdx.x;
  const float* xr = x + (size_t)t * DDIM;
  float acc[NEXP];
#pragma unroll
  for (int e = 0; e < NEXP; ++e) acc[e] = 0.f;
  for (int d0 = lane * 4; d0 < DDIM; d0 += 256) {
    float4 xv = *(const float4*)(xr + d0);
    const float* rwp = rw + (size_t)d0 * NEXP;
#pragma unroll
    for (int e = 0; e < NEXP; ++e)
      acc[e] += xv.x * rwp[e] + xv.y * rwp[NEXP + e] +
                xv.z * rwp[2 * NEXP + e] + xv.w * rwp[3 * NEXP + e];
  }
#pragma unroll
  for (int e = 0; e < NEXP; ++e) {
#pragma unroll
    for (int off = 32; off >= 1; off >>= 1) acc[e] += __shfl_xor(acc[e], off, 64);
  }
  if (lane == 0) {
    int i0 = 0; float m0 = acc[0];
#pragma unroll
    for (int e = 1; e < NEXP; ++e) if (acc[e] > m0) { m0 = acc[e]; i0 = e; }
    int i1 = -1; float m1 = -3.4e38f;
#pragma unroll
    for (int e = 0; e < NEXP; ++e) if (e != i0 && acc[e] > m1) { m1 = acc[e]; i1 = e; }
    float w0 = 1.f / (1.f + __expf(m1 - m0));
    float w1 = 1.f - w0;
    tidx[2 * t] = i0;     twt[2 * t] = w0;
    tidx[2 * t + 1] = i1; twt[2 * t + 1] = w1;
    atomicAdd(&ctl[8 + i0], 1);
    atomicAdd(&ctl[8 + i1], 1);
  }
}

__global__ void plan_k(int* ctl) {
  if (threadIdx.x != 0 || blockIdx.x != 0) return;
  int off = 0, nt = 0;
  for (int e = 0; e < NEXP; ++e) {
    int c = ctl[8 + e];
    ctl[24 + e] = off;
    ctl[16 + e] = off;
    int ntile = (c + 127) >> 7;
    for (int j = 0; j < ntile; ++j) {
      ctl[64 + nt] = e;
      ctl[160 + nt] = off + j * 128;
      ctl[256 + nt] = off + c;
      ++nt;
    }
    off += c;
  }
  ctl[24 + NEXP] = off;
  ctl[0] = nt;
}

__global__ void scatter_k(const int* __restrict__ tidx, const float* __restrict__ twt,
                          int* __restrict__ ctl, int* __restrict__ stok,
                          float* __restrict__ swt) {
  int t = blockIdx.x * blockDim.x + threadIdx.x;
  if (t >= T_TOK) return;
#pragma unroll
  for (int k = 0; k < 2; ++k) {
    int e = tidx[2 * t + k];
    int p = atomicAdd(&ctl[16 + e], 1);
    stok[p] = t;
    swt[p] = twt[2 * t + k];
  }
}

__global__ void cvt_k(const float* __restrict__ in, ushort* __restrict__ out) {
  long long i = ((long long)blockIdx.x * blockDim.x + threadIdx.x) * 8;
  float4 a = *(const float4*)(in + i);
  float4 b = *(const float4*)(in + i + 4);
  ushort4 o0 = { f2bf(a.x), f2bf(a.y), f2bf(a.z), f2bf(a.w) };
  ushort4 o1 = { f2bf(b.x), f2bf(b.y), f2bf(b.z), f2bf(b.w) };
  *(ushort4*)(out + i) = o0;
  *(ushort4*)(out + i + 4) = o1;
}

// [R][C] f32 -> [C][R] bf16 transpose+convert; slice strides explicit
__global__ void tcvt_k(const float* __restrict__ in, ushort* __restrict__ out,
                       int R, int C, long long inZ, long long outZ) {
  __shared__ float tile[64][65];
  in  += (size_t)blockIdx.z * inZ;
  out += (size_t)blockIdx.z * outZ;
  int c0 = blockIdx.x * 64, r0 = blockIdx.y * 64;
  int tx = threadIdx.x & 15, ty = threadIdx.x >> 4;
#pragma unroll
  for (int i = 0; i < 4; ++i) {
    float4 v = *(const float4*)(in + (size_t)(r0 + ty + 16 * i) * C + c0 + tx * 4);
    tile[ty + 16 * i][tx * 4 + 0] = v.x;
    tile[ty + 16 * i][tx * 4 + 1] = v.y;
    tile[ty + 16 * i][tx * 4 + 2] = v.z;
    tile[ty + 16 * i][tx * 4 + 3] = v.w;
  }
  __syncthreads();
#pragma unroll
  for (int i = 0; i < 4; ++i) {
    ushort4 o = { f2bf(tile[tx * 4 + 0][ty + 16 * i]),
                  f2bf(tile[tx * 4 + 1][ty + 16 * i]),
                  f2bf(tile[tx * 4 + 2][ty + 16 * i]),
                  f2bf(tile[tx * 4 + 3][ty + 16 * i]) };
    *(ushort4*)(out + (size_t)(c0 + ty + 16 * i) * R + r0 + tx * 4) = o;
  }
}

// ======== fused gate+up GEMM, 128x128, K-step 32, double-buffered, swizzled LDS ========
// LDS swizzle: logical (row, kgroup g) stored at phys slot g ^ ((row>>1)&3)  (16B slots).
// Stage: linear LDS dest (gload_lds requirement), pre-swizzled global k-offset.
template <bool ROUTED>
__global__ __launch_bounds__(256, 2) void gateup_k(
    const ushort* __restrict__ Ax, const ushort* __restrict__ BgT,
    const ushort* __restrict__ BuT, ushort* __restrict__ Hout,
    const int* __restrict__ ctl, const int* __restrict__ stok, int N) {
  __shared__ ushort As[2][128 * 32];
  __shared__ ushort Bgs[2][128 * 32];
  __shared__ ushort Bus[2][128 * 32];
  __shared__ int toks[128];

  int nwg = gridDim.x * gridDim.y;
  int wg = xcd_swz(blockIdx.y * gridDim.x + blockIdx.x, nwg);
  int mt = wg % gridDim.x, ntt = wg / gridDim.x;

  int tid = threadIdx.x;
  int row0, nrows;
  const ushort *Bg, *Bu;
  if (ROUTED) {
    if (mt >= ctl[0]) return;
    row0 = ctl[160 + mt];
    int end = ctl[256 + mt];
    nrows = end - row0; if (nrows > 128) nrows = 128;
    size_t es = (size_t)ctl[64 + mt] * HDIM * DDIM;
    Bg = BgT + es; Bu = BuT + es;
    if (tid < 128) toks[tid] = (tid < nrows) ? stok[row0 + tid] : 0;
  } else {
    row0 = mt * 128; nrows = 128;
    Bg = BgT; Bu = BuT;
    if (tid < 128) toks[tid] = row0 + tid;
  }
  int col0 = ntt * 128;
  __syncthreads();

  int srow = tid >> 2;
  int sslot = (tid & 3) ^ ((tid >> 3) & 3);  // pre-swizzled k-group for staging
  const ushort* aS0 = Ax + (size_t)toks[srow] * DDIM + sslot * 8;
  const ushort* aS1 = Ax + (size_t)toks[64 + srow] * DDIM + sslot * 8;
  const ushort* bgS0 = Bg + (size_t)(col0 + srow) * DDIM + sslot * 8;
  const ushort* bgS1 = Bg + (size_t)(col0 + 64 + srow) * DDIM + sslot * 8;
  const ushort* buS0 = Bu + (size_t)(col0 + srow) * DDIM + sslot * 8;
  const ushort* buS1 = Bu + (size_t)(col0 + 64 + srow) * DDIM + sslot * 8;

  int lane = tid & 63, w = tid >> 6;
  int g = lane >> 4, r16 = lane & 15;
  int xg = (g ^ ((r16 >> 1) & 3)) * 8;  // swizzled phys slot offset for ds_read
  int wr = (w >> 1) * 64, wc = (w & 1) * 64;

  f32x4 accg[4][4], accu[4][4];
  f32x4 z = {0.f, 0.f, 0.f, 0.f};
#pragma unroll
  for (int i = 0; i < 4; ++i)
#pragma unroll
    for (int j = 0; j < 4; ++j) { accg[i][j] = z; accu[i][j] = z; }

#define STAGE_GU(buf, k0)                                  \
  {                                                         \
    gload16(aS0 + (k0), &As[buf][tid * 8]);                 \
    gload16(aS1 + (k0), &As[buf][(256 + tid) * 8]);         \
    gload16(bgS0 + (k0), &Bgs[buf][tid * 8]);               \
    gload16(bgS1 + (k0), &Bgs[buf][(256 + tid) * 8]);       \
    gload16(buS0 + (k0), &Bus[buf][tid * 8]);               \
    gload16(buS1 + (k0), &Bus[buf][(256 + tid) * 8]);       \
  }
#define COMPUTE_GU(buf)                                                            \
  {                                                                                 \
    bf16x8 af[4], bgf[4], buf_[4];                                                  \
    _Pragma("unroll")                                                               \
    for (int mf = 0; mf < 4; ++mf)                                                  \
      af[mf] = *(const bf16x8*)(&As[buf][(wr + mf * 16 + r16) * 32 + xg]);          \
    _Pragma("unroll")                                                               \
    for (int nf = 0; nf < 4; ++nf) {                                                \
      bgf[nf] = *(const bf16x8*)(&Bgs[buf][(wc + nf * 16 + r16) * 32 + xg]);        \
      buf_[nf] = *(const bf16x8*)(&Bus[buf][(wc + nf * 16 + r16) * 32 + xg]);       \
    }                                                                               \
    _Pragma("unroll")                                                               \
    for (int mf = 0; mf < 4; ++mf)                                                  \
      _Pragma("unroll")                                                             \
      for (int nf = 0; nf < 4; ++nf) {                                              \
        accg[mf][nf] = __builtin_amdgcn_mfma_f32_16x16x32_bf16(af[mf], bgf[nf], accg[mf][nf], 0, 0, 0); \
        accu[mf][nf] = __builtin_amdgcn_mfma_f32_16x16x32_bf16(af[mf], buf_[nf], accu[mf][nf], 0, 0, 0); \
      }                                                                             \
  }

  STAGE_GU(0, 0);
  __syncthreads();
  int cur = 0;
  for (int k0 = 32; k0 < DDIM; k0 += 32) {
    STAGE_GU(cur ^ 1, k0);   // prefetch next while computing current
    COMPUTE_GU(cur);
    __syncthreads();         // drains vmcnt(0): prefetch landed
    cur ^= 1;
  }
  COMPUTE_GU(cur);

#pragma unroll
  for (int mf = 0; mf < 4; ++mf) {
#pragma unroll
    for (int j = 0; j < 4; ++j) {
      int rloc = wr + mf * 16 + g * 4 + j;  // C/D row map (m89-verified)
      if (rloc < nrows) {
        size_t obase = (size_t)(row0 + rloc) * N + col0 + wc;
#pragma unroll
        for (int nf = 0; nf < 4; ++nf) {
          float gv = accg[mf][nf][j];
          float uv = accu[mf][nf][j];
          float hv = gv / (1.f + __expf(-gv)) * uv;
          Hout[obase + nf * 16 + r16] = f2bf(hv);
        }
      }
    }
  }
#undef STAGE_GU
#undef COMPUTE_GU
}

// ======== down-proj GEMM, 128x128, K-step 32, double-buffered, swizzled LDS ========
template <bool ROUTED>
__global__ __launch_bounds__(256, 3) void down_k(
    const ushort* __restrict__ Ah, const ushort* __restrict__ BdT,
    float* __restrict__ Out, const int* __restrict__ ctl,
    const int* __restrict__ stok, const float* __restrict__ swt, int Ktot) {
  __shared__ ushort As[2][128 * 32];
  __shared__ ushort Bs[2][128 * 32];
  __shared__ int tokl[128];
  __shared__ float wtl[128];

  int nwg = gridDim.x * gridDim.y;
  int wg = xcd_swz(blockIdx.y * gridDim.x + blockIdx.x, nwg);
  int mt = wg % gridDim.x, ntt = wg / gridDim.x;

  int tid = threadIdx.x;
  int row0, nrows;
  const ushort* Bd;
  if (ROUTED) {
    if (mt >= ctl[0]) return;
    row0 = ctl[160 + mt];
    int end = ctl[256 + mt];
    nrows = end - row0; if (nrows > 128) nrows = 128;
    Bd = BdT + (size_t)ctl[64 + mt] * DDIM * HDIM;
    if (tid < 128) {
      bool v = tid < nrows;
      tokl[tid] = v ? stok[row0 + tid] : 0;
      wtl[tid] = v ? swt[row0 + tid] : 0.f;
    }
  } else {
    row0 = mt * 128; nrows = 128;
    Bd = BdT;
  }
  int col0 = ntt * 128;
  __syncthreads();

  int srow = tid >> 2;
  int sslot = (tid & 3) ^ ((tid >> 3) & 3);
  const ushort* aS0 = Ah + (size_t)(row0 + srow) * Ktot + sslot * 8;
  const ushort* aS1 = Ah + (size_t)(row0 + 64 + srow) * Ktot + sslot * 8;
  const ushort* bS0 = Bd + (size_t)(col0 + srow) * Ktot + sslot * 8;
  const ushort* bS1 = Bd + (size_t)(col0 + 64 + srow) * Ktot + sslot * 8;

  int lane = tid & 63, w = tid >> 6;
  int g = lane >> 4, r16 = lane & 15;
  int xg = (g ^ ((r16 >> 1) & 3)) * 8;
  int wr = (w >> 1) * 64, wc = (w & 1) * 64;

  f32x4 acc[4][4];
  f32x4 z = {0.f, 0.f, 0.f, 0.f};
#pragma unroll
  for (int i = 0; i < 4; ++i)
#pragma unroll
    for (int j = 0; j < 4; ++j) acc[i][j] = z;

#define STAGE_D(buf, k0)                                   \
  {                                                         \
    gload16(aS0 + (k0), &As[buf][tid * 8]);                 \
    gload16(aS1 + (k0), &As[buf][(256 + tid) * 8]);         \
    gload16(bS0 + (k0), &Bs[buf][tid * 8]);                 \
    gload16(bS1 + (k0), &Bs[buf][(256 + tid) * 8]);         \
  }
#define COMPUTE_D(buf)                                                             \
  {                                                                                 \
    bf16x8 af[4], bf_[4];                                                           \
    _Pragma("unroll")                                                               \
    for (int mf = 0; mf < 4; ++mf)                                                  \
      af[mf] = *(const bf16x8*)(&As[buf][(wr + mf * 16 + r16) * 32 + xg]);          \
    _Pragma("unroll")                                                               \
    for (int nf = 0; nf < 4; ++nf)                                                  \
      bf_[nf] = *(const bf16x8*)(&Bs[buf][(wc + nf * 16 + r16) * 32 + xg]);         \
    _Pragma("unroll")                                                               \
    for (int mf = 0; mf < 4; ++mf)                                                  \
      _Pragma("unroll")                                                             \
      for (int nf = 0; nf < 4; ++nf)                                                \
        acc[mf][nf] = __builtin_amdgcn_mfma_f32_16x16x32_bf16(af[mf], bf_[nf], acc[mf][nf], 0, 0, 0); \
  }

  STAGE_D(0, 0);
  __syncthreads();
  int cur = 0;
  for (int k0 = 32; k0 < Ktot; k0 += 32) {
    STAGE_D(cur ^ 1, k0);
    COMPUTE_D(cur);
    __syncthreads();
    cur ^= 1;
  }
  COMPUTE_D(cur);

#pragma unroll
  for (int mf = 0; mf < 4; ++mf) {
#pragma unroll
    for (int j = 0; j < 4; ++j) {
      int rloc = wr + mf * 16 + g * 4 + j;
      if (rloc < nrows) {
        if (ROUTED) {
          int t = tokl[rloc];
          float wt = wtl[rloc];
          size_t obase = (size_t)t * DDIM + col0 + wc;
#pragma unroll
          for (int nf = 0; nf < 4; ++nf)
            atomicAdd(&Out[obase + nf * 16 + r16], wt * acc[mf][nf][j]);
        } else {
          size_t obase = (size_t)(row0 + rloc) * DDIM + col0 + wc;
#pragma unroll
          for (int nf = 0; nf < 4; ++nf)
            Out[obase + nf * 16 + r16] = acc[mf][nf][j];
        }
      }
    }
  }
#undef STAGE_D
#undef COMPUTE_D
}

extern "C" void kernel_launch(void* const* d_in, const int* in_sizes, int n_in,
                              void* d_out, int out_size, void* d_ws, size_t ws_size,
                              hipStream_t stream) {
  const float* x   = (const float*)d_in[0];
  const float* rw  = (const float*)d_in[1];
  const float* wg  = (const float*)d_in[2];
  const float* wu  = (const float*)d_in[3];
  const float* wd  = (const float*)d_in[4];
  const float* swg = (const float*)d_in[5];
  const float* swu = (const float*)d_in[6];
  const float* swd = (const float*)d_in[7];
  float* out = (float*)d_out;

  char* ws = (char*)d_ws;
  size_t off = 0;
  auto alloc = [&](size_t bytes) {
    char* p = ws + off;
    off += (bytes + 4095) & ~(size_t)4095;
    return p;
  };
  int*    ctl   = (int*)alloc(4096);
  int*    tidx  = (int*)alloc(NASSIGN * 4);
  float*  twt   = (float*)alloc(NASSIGN * 4);
  int*    stok  = (int*)alloc(NASSIGN * 4);
  float*  swt_  = (float*)alloc(NASSIGN * 4);
  ushort* xbf   = (ushort*)alloc((size_t)T_TOK * DDIM * 2);
  ushort* wgT   = (ushort*)alloc((size_t)NEXP * HDIM * DDIM * 2);
  ushort* wuT   = (ushort*)alloc((size_t)NEXP * HDIM * DDIM * 2);
  ushort* wdT   = (ushort*)alloc((size_t)NEXP * DDIM * HDIM * 2);
  ushort* swgT  = (ushort*)alloc((size_t)HSDIM * DDIM * 2);
  ushort* swuT  = (ushort*)alloc((size_t)HSDIM * DDIM * 2);
  ushort* swdT  = (ushort*)alloc((size_t)DDIM * HSDIM * 2);
  ushort* hr    = (ushort*)alloc((size_t)(NASSIGN + 256) * HDIM * 2);  // +pad for tail staging
  ushort* hs    = (ushort*)alloc((size_t)T_TOK * HSDIM * 2);
  (void)alloc(1 << 20);  // guard pad
  if (off > ws_size) return;

  // routing chain
  zero_k<<<1, 256, 0, stream>>>(ctl);
  router_k<<<T_TOK, 64, 0, stream>>>(x, rw, ctl, tidx, twt);
  plan_k<<<1, 64, 0, stream>>>(ctl);
  scatter_k<<<16, 256, 0, stream>>>(tidx, twt, ctl, stok, swt_);

  // precision/layout prepasses
  cvt_k<<<(T_TOK * DDIM / 8) / 256, 256, 0, stream>>>(x, xbf);
  tcvt_k<<<dim3(HDIM / 64, DDIM / 64, NEXP), 256, 0, stream>>>(
      wg, wgT, DDIM, HDIM, (long long)DDIM * HDIM, (long long)HDIM * DDIM);
  tcvt_k<<<dim3(HDIM / 64, DDIM / 64, NEXP), 256, 0, stream>>>(
      wu, wuT, DDIM, HDIM, (long long)DDIM * HDIM, (long long)HDIM * DDIM);
  tcvt_k<<<dim3(DDIM / 64, HDIM / 64, NEXP), 256, 0, stream>>>(
      wd, wdT, HDIM, DDIM, (long long)HDIM * DDIM, (long long)DDIM * HDIM);
  tcvt_k<<<dim3(HSDIM / 64, DDIM / 64, 1), 256, 0, stream>>>(
      swg, swgT, DDIM, HSDIM, 0, 0);
  tcvt_k<<<dim3(HSDIM / 64, DDIM / 64, 1), 256, 0, stream>>>(
      swu, swuT, DDIM, HSDIM, 0, 0);
  tcvt_k<<<dim3(DDIM / 64, HSDIM / 64, 1), 256, 0, stream>>>(
      swd, swdT, HSDIM, DDIM, 0, 0);

  // fused SwiGLU front (gate+up+silu in epilogue)
  gateup_k<true><<<dim3(MAXTILES, HDIM / 128), 256, 0, stream>>>(xbf, wgT, wuT, hr, ctl, stok, HDIM);
  gateup_k<false><<<dim3(T_TOK / 128, HSDIM / 128), 256, 0, stream>>>(xbf, swgT, swuT, hs, ctl, stok, HSDIM);

  // down: shared stores all of out, then routed atomically adds
  down_k<false><<<dim3(T_TOK / 128, DDIM / 128), 256, 0, stream>>>(hs, swdT, out, ctl, stok, swt_, HSDIM);
  down_k<true><<<dim3(MAXTILES, DDIM / 128), 256, 0, stream>>>(hr, wdT, out, ctl, stok, swt_, HDIM);
}